// Round 19
// baseline (384.303 us; speedup 1.0000x reference)
//
#include <hip/hip_runtime.h>
#include <math.h>

typedef _Float16 f16;
typedef _Float16 f16x4v __attribute__((ext_vector_type(4)));
typedef _Float16 f16x8 __attribute__((ext_vector_type(8)));
typedef float f32x4 __attribute__((ext_vector_type(4)));

#define NB 16      // batch
#define NT 16      // time steps
#define NH 64
#define NW 64
#define NF 64      // features
#define NG 256     // 4*F
#define HWF ((size_t)NH * NW * NF)          // 262144
#define OUT_BSTRIDE ((size_t)NT * HWF)      // d_out batch stride
#define RS2 8448                            // LDS row stride = 66 * 128 B (x-padded)
#define WSTEP ((size_t)18432)               // per-step wf2 size in f16x8 chunks (hi-only)

#define MFMA(a, b, c) __builtin_amdgcn_mfma_f32_16x16x32_f16((a), (b), (c), 0, 0, 0)

__device__ __forceinline__ void gload_lds16(const void* g, void* l) {
    __builtin_amdgcn_global_load_lds(
        (const __attribute__((address_space(1))) unsigned int*)(g),
        (__attribute__((address_space(3))) unsigned int*)(l), 16, 0, 0);
}

__device__ __forceinline__ float hsig(float x) {
    return fminf(fmaxf(0.2f * x + 0.5f, 0.0f), 1.0f);
}

// fast tanh via v_exp_f32 (rounds 8-18 verified absmax-neutral)
__device__ __forceinline__ float ftanh(float x) {
    float t = __builtin_amdgcn_exp2f(x * 2.885390081777927f);
    return 1.0f - 2.0f * __builtin_amdgcn_rcpf(t + 1.0f);
}

// ---- prologue 1: fuse W+U -> f16 hi-only, gate-major lane-ordered chunks,
// via LDS transpose. One block per (t, tap, kk): coalesced float4 reads of
// k/rk (lanes span 1KB contiguous), padded-LDS transpose, coalesced f16x8
// chunk writes. Chunk layout identical to round 18:
//   chunk = t*WSTEP + (tap*2+kk)*1024 + cb*64 + lane
//   cb = fgrp*4 + gate ; lane = lg*16 + lm ; cout = gate*64 + fgrp*16 + lm
//   element j = cin kk*32 + lg*8 + j
__global__ void fuse_w_lds(const float* __restrict__ k, const float* __restrict__ rk,
                           f16* __restrict__ wf2) {
    __shared__ f16 lt[32][264];            // [cin_local][cout], +8 pad

    const int blk = blockIdx.x;            // 0..287 = tt*2 + kk
    const int kk  = blk & 1;
    const int tt  = blk >> 1;              // t*9 + tap
    const int tap = tt % 9;
    const int t   = tt / 9;
    const int tid = threadIdx.x;

    const float* ks = k  + (size_t)tt * NF * NG;
    const float* rs = rk + (size_t)tt * NF * NG;

    const int c4 = (tid & 63) * 4;         // cout base (coalesced across lanes)
    const int r0 = (tid >> 6) * 8;         // cin_local base
#pragma unroll
    for (int r = 0; r < 8; ++r) {
        const int cin = kk * 32 + r0 + r;
        const float4 a = *(const float4*)&ks[(size_t)cin * NG + c4];
        const float4 b = *(const float4*)&rs[(size_t)cin * NG + c4];
        lt[r0 + r][c4 + 0] = (f16)(a.x + b.x);
        lt[r0 + r][c4 + 1] = (f16)(a.y + b.y);
        lt[r0 + r][c4 + 2] = (f16)(a.z + b.z);
        lt[r0 + r][c4 + 3] = (f16)(a.w + b.w);
    }
    __syncthreads();

    const int lane = tid & 63;
    const int lm = lane & 15, lg = lane >> 4;
#pragma unroll
    for (int i = 0; i < 4; ++i) {
        const int cb   = (tid >> 6) + i * 4;            // 0..15
        const int cout = (cb & 3) * 64 + (cb >> 2) * 16 + lm;
        f16 v[8];
#pragma unroll
        for (int j = 0; j < 8; ++j)
            v[j] = lt[lg * 8 + j][cout];
        const size_t chunk = (size_t)t * WSTEP + (size_t)(tap * 2 + kk) * 1024 +
                             (size_t)cb * 64 + lane;
        *(f16x8*)&wf2[chunk * 8] = *(f16x8*)v;          // coalesced across lanes
    }
}

// ---- prologue 2: h0 f32->f16 ([pos][f]) and c0 f32->f16 transposed [b][y][f][x]
__global__ void convert_states(const float* __restrict__ h0, f16* __restrict__ h2,
                               const float* __restrict__ c0, f16* __restrict__ cbuf) {
    const int blk = blockIdx.x;
    const int tid = threadIdx.x;
    if (blk < 4096) {
        int i = blk * 256 + tid;
        float4 v = ((const float4*)h0)[i];
        f16x4v o = { (f16)v.x, (f16)v.y, (f16)v.z, (f16)v.w };
        *(f16x4v*)&h2[(size_t)i * 4] = o;
    } else {
        // c0 transpose-convert (reads coalesced over f)
        int i = (blk - 4096) * 256 + tid;      // [0, 1048576)
        int bgy = i >> 10;
        int rem = i & 1023;
        int x4  = rem >> 6;
        int f   = rem & 63;
        const float* src = c0 + (size_t)bgy * 4096 + (size_t)x4 * 256 + f;
        f16x4v o = { (f16)src[0], (f16)src[64], (f16)src[128], (f16)src[192] };
        *(f16x4v*)&cbuf[((size_t)bgy * 64 + f) * 64 + x4 * 4] = o;
    }
}

// ---- one ConvLSTM step (round-15/18 proven structure, unchanged math):
// 256 blocks (1/CU), 512 thr = 8 waves (2m x 4n); tile 4 rows x 64 x x 256 couts;
// gate-major B -> in-register LSTM epilogue; 1 barrier/step; batch-sticky XCD.
__global__ void __launch_bounds__(512, 2)
convlstm_mfma_step(const f16* __restrict__ h2in, f16* __restrict__ h2out,
                   f16* __restrict__ cbuf,
                   float* __restrict__ hout,        // d_out + t*HWF
                   const f16* __restrict__ wt,
                   const float* __restrict__ bias,  // [256] for this t
                   int last)                        // t == NT-1: skip state stores
{
    __shared__ __align__(16) unsigned char lds[6 * RS2];   // 50688 B

    const int tid  = threadIdx.x;
    const int w    = tid >> 6;
    const int lane = tid & 63;

    const int id = blockIdx.x;
    const int bb = ((id & 7) << 1) + ((id >> 7) & 1);
    const int y0 = ((id >> 3) & 15) * 4;

    const int wm = w >> 2;
    const int wn = w & 3;
    const int lm = lane & 15;
    const int lg = lane >> 4;

    const f16x8* wb = (const f16x8*)wt + (size_t)(wn * 4) * 64 + lane;

    // prefetch it=0 B fragments (independent of staging)
    f16x8 bh[4];
#pragma unroll
    for (int nf = 0; nf < 4; ++nf)
        bh[nf] = wb[nf * 64];

    // prefetch c-state: 8 x f16x4 vector loads (x-contiguous cbuf)
    const int f = wn * 16 + lm;
    f16x4v cp[8];
#pragma unroll
    for (int mf = 0; mf < 8; ++mf) {
        const int gy = y0 + wm * 2 + (mf >> 2);
        const int xb = (mf & 3) * 16 + lg * 4;
        cp[mf] = *(const f16x4v*)&cbuf[(((size_t)bb * NH + gy) * NF + f) * 64 + xb];
    }

    // zero the pad columns tx=0 and tx=65 (6 rows x 2 x 8 granules)
    if (tid < 96) {
        int row = tid >> 4, side = (tid >> 3) & 1, j = tid & 7;
        *(f16x8*)&lds[row * RS2 + side * (65 * 128) + j * 16] = (f16x8)(_Float16)0.0f;
    }

    // stage rows y0-1 .. y0+4: wave w covers x in [w*8, w*8+8) for all 6 rows
    {
        const int x = w * 8 + (lane >> 3);
        const int g = lane & 7;
        const unsigned src = ((unsigned)x << 7) +
                             ((unsigned)(g ^ ((x + 1) & 7)) << 4);
#pragma unroll
        for (int kr = 0; kr < 6; ++kr) {
            const int gy = y0 - 1 + kr;
            const unsigned dbase = kr * RS2 + 128 + w * 1024;   // wave-uniform
            if (gy >= 0 && gy < NH) {
                const unsigned char* gsrc = (const unsigned char*)h2in +
                    ((((size_t)bb * NH + gy) * NW) << 7);
                gload_lds16(gsrc + src, (void*)&lds[dbase]);
            } else {
                *(f16x8*)&lds[dbase + lane * 16] = (f16x8)(_Float16)0.0f;
            }
        }
    }
    __syncthreads();        // the ONLY barrier

    // ---------- K loop: 9 taps x 2 cin-halves, fully unrolled, 1-term f16
    f32x4 acc[8][4];
#pragma unroll
    for (int mf = 0; mf < 8; ++mf)
#pragma unroll
        for (int nf = 0; nf < 4; ++nf) acc[mf][nf] = (f32x4)0.0f;

    unsigned av[3][2];
#pragma unroll
    for (int d = 0; d < 3; ++d)
#pragma unroll
        for (int kk = 0; kk < 2; ++kk) {
            const int tx = lm + d;
            av[d][kk] = (unsigned)(tx * 128 +
                        (((kk * 4 + lg) ^ (tx & 7)) << 4));
        }

#pragma unroll
    for (int it = 0; it < 18; ++it) {
        if (it > 0) {
#pragma unroll
            for (int nf = 0; nf < 4; ++nf)
                bh[nf] = wb[(size_t)it * 1024 + nf * 64];
        }
        const int tap = it >> 1, kk = it & 1;
        const int ty = tap / 3;
        const int d  = tap - ty * 3;
        const unsigned abase = (unsigned)((wm * 2 + ty) * RS2) + av[d][kk];
        __builtin_amdgcn_s_setprio(1);
#pragma unroll
        for (int mf = 0; mf < 8; ++mf) {
            const f16x8 ah = *(const f16x8*)&lds[abase + (mf >> 2) * RS2 +
                                                 (mf & 3) * 2048];
#pragma unroll
            for (int nf = 0; nf < 4; ++nf)
                acc[mf][nf] = MFMA(ah, bh[nf], acc[mf][nf]);
        }
        __builtin_amdgcn_s_setprio(0);
    }

    // ---------- epilogue: fully in-register LSTM pointwise
    const float b0 = bias[f], b1 = bias[64 + f], b2 = bias[128 + f], b3 = bias[192 + f];

#pragma unroll
    for (int mf = 0; mf < 8; ++mf) {
        const int gy = y0 + wm * 2 + (mf >> 2);
        const int xb = (mf & 3) * 16 + lg * 4;
        const size_t hbase = ((((size_t)bb * NH + gy) * NW + xb) << 6) + f;
        f16x4v cn4, hn4;
#pragma unroll
        for (int j = 0; j < 4; ++j) {
            const float zi  = acc[mf][0][j] + b0;
            const float zfv = acc[mf][1][j] + b1;
            const float zc  = acc[mf][2][j] + b2;
            const float zo  = acc[mf][3][j] + b3;
            const float ig = hsig(zi), fg = hsig(zfv), og = hsig(zo);
            const float cn = fg * (float)cp[mf][j] + ig * ftanh(zc);
            cn4[j] = (f16)cn;
            const float hn = og * ftanh(cn);
            hn4[j] = (f16)hn;
            hout[(size_t)bb * OUT_BSTRIDE + (((size_t)gy * NW + xb + j) << 6) + f] = hn;
        }
        if (!last) {
            *(f16x4v*)&cbuf[(((size_t)bb * NH + gy) * NF + f) * 64 + xb] = cn4;
#pragma unroll
            for (int j = 0; j < 4; ++j)
                h2out[hbase + (size_t)j * 64] = hn4[j];
        }
    }
}

extern "C" void kernel_launch(void* const* d_in, const int* in_sizes, int n_in,
                              void* d_out, int out_size, void* d_ws, size_t ws_size,
                              hipStream_t stream) {
    const float* h0    = (const float*)d_in[1];
    const float* c0    = (const float*)d_in[2];
    const float* kern  = (const float*)d_in[3];
    const float* rkern = (const float*)d_in[4];
    const float* bias  = (const float*)d_in[5];
    float* out = (float*)d_out;

    f16* wf2   = (f16*)d_ws;                                  // 4.7 MB (hi only)
    f16* h2a   = wf2 + (size_t)NT * WSTEP * 8;                // 8.4 MB
    f16* h2b   = h2a + (size_t)NB * HWF;                      // 8.4 MB
    f16* cbuf  = h2b + (size_t)NB * HWF;                      // 8.4 MB (f16 c, [b][y][f][x])

    fuse_w_lds<<<dim3(NT * 9 * 2), 256, 0, stream>>>(kern, rkern, wf2);
    convert_states<<<dim3(8192), 256, 0, stream>>>(h0, h2a, c0, cbuf);

    for (int t = 0; t < NT; ++t) {
        const f16* hin = (t & 1) ? h2b : h2a;
        f16* hnx       = (t & 1) ? h2a : h2b;
        convlstm_mfma_step<<<dim3(256), 512, 0, stream>>>(
            hin, hnx, cbuf,
            out + (size_t)t * HWF,
            wf2 + (size_t)t * WSTEP * 8,
            bias + t * NG,
            (t == NT - 1) ? 1 : 0);
    }
}